// Round 13
// baseline (142.626 us; speedup 1.0000x reference)
//
#include <hip/hip_runtime.h>
#include <hip/hip_bf16.h>

// Problem constants
#define B_  16
#define C_  6
#define T_  512
#define S_  8

#define AS1 __attribute__((address_space(1)))
#define AS3 __attribute__((address_space(3)))

typedef __attribute__((ext_vector_type(8))) short bf16x8;
typedef __attribute__((ext_vector_type(4))) float f32x4;

__device__ __forceinline__ ushort f2bf(float f) {
    __hip_bfloat16 h = __float2bfloat16(f);
    return *reinterpret_cast<ushort*>(&h);
}
__device__ __forceinline__ float bfu2f(ushort u) {
    uint x = (uint)u << 16;
    union { uint u; float f; } c; c.u = x; return c.f;
}

// ---------------------------------------------------------------------------
// Two 512x512 transposes in one launch (Wk->WkT, Wv->WvT)
__global__ void transpose2(const float* __restrict__ s0, const float* __restrict__ s1,
                           float* __restrict__ d0, float* __restrict__ d1) {
    const float* src = blockIdx.z ? s1 : s0;
    float* dst = blockIdx.z ? d1 : d0;
    __shared__ float tile[32][33];
    int bx = blockIdx.x * 32, by = blockIdx.y * 32;
    int tx = threadIdx.x, ty = threadIdx.y;
    for (int i = 0; i < 32; i += 8)
        tile[ty + i][tx] = src[(long)(by + ty + i) * 512 + bx + tx];
    __syncthreads();
    for (int i = 0; i < 32; i += 8)
        dst[(long)(bx + ty + i) * 512 + by + tx] = tile[tx][ty + i];
}

// Two fp32->bf16 512x512 conversions in one launch (Wq, Wo)
__global__ void convert2(const float* __restrict__ s0, const float* __restrict__ s1,
                         ushort* __restrict__ d0, ushort* __restrict__ d1) {
    const float* s = blockIdx.y ? s1 : s0;
    ushort* d = blockIdx.y ? d1 : d0;
    int i = (blockIdx.x * 256 + threadIdx.x) * 4;
    float4 v = *(const float4*)(s + i);
    ushort4 o;
    o.x = f2bf(v.x); o.y = f2bf(v.y); o.z = f2bf(v.z); o.w = f2bf(v.w);
    *(ushort4*)(d + i) = o;
}

// ---------------------------------------------------------------------------
// K/V projections (tiny: 128 rows)
__global__ void kv_proj(const float* __restrict__ key, const float* __restrict__ value,
                        const float* __restrict__ WkT, const float* __restrict__ WvT,
                        const float* __restrict__ bk, const float* __restrict__ bv,
                        float* __restrict__ kout, float* __restrict__ vout) {
    int row = blockIdx.x;      // b*S + s
    int j = threadIdx.x;       // 0..511
    __shared__ float krow[512];
    __shared__ float vrow[512];
    krow[j] = key[(long)row * 512 + j];
    vrow[j] = value[(long)row * 512 + j];
    __syncthreads();
    float ak = bk[j], av = bv[j];
#pragma unroll 8
    for (int f = 0; f < 512; ++f) {
        ak += krow[f] * WkT[(long)f * 512 + j];
        av += vrow[f] * WvT[(long)f * 512 + j];
    }
    kout[(long)row * 512 + j] = ak;
    vout[(long)row * 512 + j] = av;
}

// ---------------------------------------------------------------------------
// MEGA-FUSED v3: block = 8 t-rows of one b; 512 threads = 8 waves; WAVE = HEAD.
// vs v2 (16 t-rows): Alds halves to 48 KB and acc halves to 3 m-frags, so TWO
// blocks fit per CU (launch_bounds(512,4) caps regs at 128 -> 4 waves/SIMD):
// block X's phase-1 HBM stream overlaps block Y's compute phases.
// A-row = c*8 + tt; in the MFMA C-layout m = mf*16 + ln16*4 + j:
//   c  = 2*mf + (ln16>>1)   (c spans frags AND lane bit 5)
//   tt = (ln16&1)*4 + j
// Partner lanes (xor 32 = flip ln16 bit1) hold the SAME (tt, d) for the other
// c-half, so mean-over-c / ss / x each need one extra shfl_xor(.,32).
__global__ __launch_bounds__(512, 4) void qattn(const float* __restrict__ query,
                                                const ushort* __restrict__ Wqbf,
                                                const float* __restrict__ bq,
                                                const float* __restrict__ kproj,
                                                const float* __restrict__ vproj,
                                                const int* __restrict__ mask,
                                                ushort* __restrict__ xout) {
    __shared__ __align__(16) ushort Alds[48 * 512];   // 48 KB
    __shared__ int mlds[64];

    const int b   = blockIdx.x >> 6;
    const int t0  = (blockIdx.x & 63) << 3;
    const int tid = threadIdx.x;
    const int h    = tid >> 6;          // wave = head
    const int lane = tid & 63;
    const int ln15 = lane & 15;
    const int ln16 = lane >> 4;
    const int hi   = ln16 >> 1;        // c-half selector
    const int nb   = h * 64;

    // ---- Phase 1: stage 48 query rows -> Alds (bf16, 8-chunk XOR row&7) ----
    if (tid < 64) mlds[tid] = mask[((long)b * 512 + t0 + (tid >> 3)) * 8 + (tid & 7)];
#pragma unroll
    for (int rep = 0; rep < 2; ++rep) {
        int item = rep * 512 + tid;
        if (rep == 1 && tid >= 256) break;    // 768 items total
        int row = item >> 4;            // 0..47 = c*8 + tt
        int kc  = (item & 15) * 32;     // float offset
        int c = row >> 3, tt = row & 7;
        const float* src = query + ((long)(b * 6 + c) * 512 + t0 + tt) * 512 + kc;
        float4 v[8];
#pragma unroll
        for (int q = 0; q < 8; ++q) v[q] = *(const float4*)(src + q * 4);
#pragma unroll
        for (int q2 = 0; q2 < 4; ++q2) {
            uint4 pk;
            pk.x = (uint)f2bf(v[2*q2].x)   | ((uint)f2bf(v[2*q2].y)   << 16);
            pk.y = (uint)f2bf(v[2*q2].z)   | ((uint)f2bf(v[2*q2].w)   << 16);
            pk.z = (uint)f2bf(v[2*q2+1].x) | ((uint)f2bf(v[2*q2+1].y) << 16);
            pk.w = (uint)f2bf(v[2*q2+1].z) | ((uint)f2bf(v[2*q2+1].w) << 16);
            int c8 = (kc >> 3) + q2;
            *(uint4*)&Alds[row * 512 + (((c8 & 7) ^ (row & 7)) << 3) + ((c8 >> 3) << 6)] = pk;
        }
    }
    __syncthreads();

    // ---- Phase 2: q-GEMM, q stays in acc (3 m-frags x 4 n-frags) ----
    f32x4 acc[3][4] = {};
    uint4 br2[2][4];
#pragma unroll
    for (int nf = 0; nf < 4; ++nf) {
        br2[0][nf] = *(const uint4*)(Wqbf + (long)(nb + nf * 16 + ln15) * 512 + ln16 * 8);
        br2[1][nf] = *(const uint4*)(Wqbf + (long)(nb + nf * 16 + ln15) * 512 + 32 + ln16 * 8);
    }
#pragma unroll
    for (int kb = 0; kb < 16; ++kb) {
        bf16x8 af[3];
#pragma unroll
        for (int mf = 0; mf < 3; ++mf) {
            int row = mf * 16 + ln15;
            int c8  = kb * 4 + ln16;
            af[mf] = *(const bf16x8*)&Alds[row * 512 + (((c8 & 7) ^ (row & 7)) << 3) + ((c8 >> 3) << 6)];
        }
#pragma unroll
        for (int mf = 0; mf < 3; ++mf)
#pragma unroll
            for (int nf = 0; nf < 4; ++nf)
                acc[mf][nf] = __builtin_amdgcn_mfma_f32_16x16x32_bf16(
                    af[mf], *(const bf16x8*)&br2[kb & 1][nf], acc[mf][nf], 0, 0, 0);
        if (kb < 14) {
#pragma unroll
            for (int nf = 0; nf < 4; ++nf)
                br2[kb & 1][nf] = *(const uint4*)(Wqbf + (long)(nb + nf * 16 + ln15) * 512
                                                  + (kb + 2) * 32 + ln16 * 8);
        }
    }
    {
        float bqv[4];
#pragma unroll
        for (int nf = 0; nf < 4; ++nf) bqv[nf] = bq[nb + nf * 16 + ln15];
#pragma unroll
        for (int mf = 0; mf < 3; ++mf)
#pragma unroll
            for (int nf = 0; nf < 4; ++nf)
#pragma unroll
                for (int j = 0; j < 4; ++j) acc[mf][nf][j] += bqv[nf];
    }
    __syncthreads();   // all waves done reading Alds (freed for x-stage)

    // ---- Phase 3: q1 = mean over c (3 local c's + partner's 3 via xor32) ----
    f32x4 q1f[4];
#pragma unroll
    for (int nf = 0; nf < 4; ++nf) {
        f32x4 s = acc[0][nf] + acc[1][nf] + acc[2][nf];
#pragma unroll
        for (int j = 0; j < 4; ++j) {
            float v = s[j];
            v += __shfl_xor(v, 32);
            q1f[nf][j] = v * (1.0f / 6.0f);
        }
    }

    // ---- Phase 4: stage-1 attention (head-local; sc/attn merged in place) ----
    float sc[4][8];
#pragma unroll
    for (int s = 0; s < 8; ++s) {
        float kv[4];
#pragma unroll
        for (int nf = 0; nf < 4; ++nf)
            kv[nf] = kproj[(long)(b * 8 + s) * 512 + nb + nf * 16 + ln15];
#pragma unroll
        for (int j = 0; j < 4; ++j) {
            float p = q1f[0][j] * kv[0] + q1f[1][j] * kv[1]
                    + q1f[2][j] * kv[2] + q1f[3][j] * kv[3];
            p += __shfl_xor(p, 1); p += __shfl_xor(p, 2);
            p += __shfl_xor(p, 4); p += __shfl_xor(p, 8);
            sc[j][s] = p * 0.125f;
        }
    }
#pragma unroll
    for (int j = 0; j < 4; ++j) {
        int tt = (ln16 & 1) * 4 + j;
        int mk[8];
        float mx = -1e30f;
#pragma unroll
        for (int s = 0; s < 8; ++s) {
            mk[s] = mlds[tt * 8 + s];
            if (mk[s] == 0) sc[j][s] = -1e30f;
            mx = fmaxf(mx, sc[j][s]);
        }
        float sum = 0.f;
#pragma unroll
        for (int s = 0; s < 8; ++s) {
            float e = __expf(sc[j][s] - mx);
            sc[j][s] = e;
            sum += e;
        }
        float inv = 1.0f / sum;
#pragma unroll
        for (int s = 0; s < 8; ++s) sc[j][s] = mk[s] ? sc[j][s] * inv : 0.f;
    }
    f32x4 pcf[4] = {};
#pragma unroll
    for (int s = 0; s < 8; ++s) {
        float vv[4];
#pragma unroll
        for (int nf = 0; nf < 4; ++nf)
            vv[nf] = vproj[(long)(b * 8 + s) * 512 + nb + nf * 16 + ln15];
#pragma unroll
        for (int nf = 0; nf < 4; ++nf)
#pragma unroll
            for (int j = 0; j < 4; ++j) pcf[nf][j] += sc[j][s] * vv[nf];
    }

    // ---- Phase 5: ss + softmax over 6 c (3 local + 3 partner via xor32) ----
    float pown[3][4], poth[3][4];
#pragma unroll
    for (int mf = 0; mf < 3; ++mf)
#pragma unroll
        for (int j = 0; j < 4; ++j) {
            float p = pcf[0][j] * acc[mf][0][j] + pcf[1][j] * acc[mf][1][j]
                    + pcf[2][j] * acc[mf][2][j] + pcf[3][j] * acc[mf][3][j];
            p += __shfl_xor(p, 1); p += __shfl_xor(p, 2);
            p += __shfl_xor(p, 4); p += __shfl_xor(p, 8);
            pown[mf][j] = p * 0.125f;
        }
#pragma unroll
    for (int mf = 0; mf < 3; ++mf)
#pragma unroll
        for (int j = 0; j < 4; ++j)
            poth[mf][j] = __shfl_xor(pown[mf][j], 32);
    float wsm[3][4];   // softmax weight for this lane's own c = 2mf+hi
#pragma unroll
    for (int j = 0; j < 4; ++j) {
        float mx = fmaxf(fmaxf(fmaxf(pown[0][j], pown[1][j]), fmaxf(pown[2][j], poth[0][j])),
                         fmaxf(poth[1][j], poth[2][j]));
        float eo[3];
        float sum = 0.f;
#pragma unroll
        for (int mf = 0; mf < 3; ++mf) {
            eo[mf] = __expf(pown[mf][j] - mx);
            sum += eo[mf] + __expf(poth[mf][j] - mx);
        }
        float inv = 1.0f / sum;
#pragma unroll
        for (int mf = 0; mf < 3; ++mf) wsm[mf][j] = eo[mf] * inv;
    }

    // ---- Phase 6: x = sum_c a2_c * q_c ; stage via LDS; coalesced store ----
    ushort* xstage = Alds;   // 8 rows x 512 bf16, Alds is dead
#pragma unroll
    for (int nf = 0; nf < 4; ++nf)
#pragma unroll
        for (int j = 0; j < 4; ++j) {
            float xp = wsm[0][j] * acc[0][nf][j] + wsm[1][j] * acc[1][nf][j]
                     + wsm[2][j] * acc[2][nf][j];
            xp += __shfl_xor(xp, 32);           // add partner c-half
            if ((ln16 & 2) == 0)
                xstage[((ln16 & 1) * 4 + j) * 512 + nb + nf * 16 + ln15] = f2bf(xp);
        }
    __syncthreads();
    {
        int row = tid >> 6;
        int off = (tid & 63) * 8;
        uint4 v0 = *(const uint4*)&xstage[row * 512 + off];
        ushort* dst = xout + ((long)(b * 512 + t0 + row)) * 512 + off;
        *(uint4*)dst = v0;
    }
}

// ---------------------------------------------------------------------------
// MFMA bf16 GEMM (R9 structure) — output projection only (ABF16 path).
template <int ABF16, int OUTBF>
__global__ __launch_bounds__(256, ABF16 ? 2 : 3)
void gemm_mfma(const void* __restrict__ Ain,
               const ushort* __restrict__ Wbf,
               const float* __restrict__ bias,
               void* __restrict__ out, int mpanels) {
    __shared__ __align__(16) ushort lds[32768];

    const int bid = blockIdx.x;
    const int cpx = (mpanels * 4) >> 3;
    const int swz = (bid & 7) * cpx + (bid >> 3);
    const int bm = (swz >> 2) * 128;
    const int bn = (swz & 3) * 128;

    const int tid  = threadIdx.x;
    const int lane = tid & 63;
    const int wv   = tid >> 6;
    const int wm   = (wv >> 1) * 64;
    const int wn   = (wv & 1) * 64;
    const int ln15 = lane & 15;
    const int ln16 = lane >> 4;

    auto GLDS = [&](const ushort* gbase, int rowbase, ushort* ldsbase, int k0) {
        int rb = wv * 32 + (lane >> 3);
        int c  = lane & 7;
#pragma unroll
        for (int i = 0; i < 4; ++i) {
            int r = rb + i * 8;
            const ushort* src = gbase + (long)(rowbase + r) * 512 + k0 + ((c ^ (r & 7)) << 3);
            ushort* dst = ldsbase + wv * 2048 + i * 512;
            __builtin_amdgcn_global_load_lds((AS1 const void*)src, (AS3 void*)dst, 16, 0, 0);
        }
    };

    ushort* asb0 = lds;
    ushort* asb1 = lds + 8192;
    ushort* wsb[2] = { lds + 16384, lds + 24576 };

    f32x4 acc[4][4] = {};

    auto MFMA_PHASE = [&](ushort* Asb, ushort* Wsb) {
        __builtin_amdgcn_s_setprio(1);
#pragma unroll
        for (int kj = 0; kj < 2; ++kj) {
            bf16x8 af[4], bfv[4];
#pragma unroll
            for (int mi = 0; mi < 4; ++mi) {
                int row = wm + mi * 16 + ln15;
                int ch  = kj * 4 + ln16;
                af[mi] = *(const bf16x8*)&Asb[row * 64 + ((ch ^ (row & 7)) << 3)];
            }
#pragma unroll
            for (int ni = 0; ni < 4; ++ni) {
                int row = wn + ni * 16 + ln15;
                int ch  = kj * 4 + ln16;
                bfv[ni] = *(const bf16x8*)&Wsb[row * 64 + ((ch ^ (row & 7)) << 3)];
            }
#pragma unroll
            for (int mi = 0; mi < 4; ++mi)
#pragma unroll
                for (int ni = 0; ni < 4; ++ni)
                    acc[mi][ni] = __builtin_amdgcn_mfma_f32_16x16x32_bf16(
                        af[mi], bfv[ni], acc[mi][ni], 0, 0, 0);
        }
        __builtin_amdgcn_s_setprio(0);
    };

    GLDS((const ushort*)Ain, bm, asb0, 0);
    GLDS(Wbf, bn, wsb[0], 0);
    asm volatile("s_waitcnt vmcnt(0) lgkmcnt(0)" ::: "memory");
    __builtin_amdgcn_sched_barrier(0);
    __builtin_amdgcn_s_barrier();
    asm volatile("" ::: "memory");
#pragma unroll
    for (int kt = 0; kt < 8; ++kt) {
        ushort* Asb = (kt & 1) ? asb1 : asb0;
        ushort* nAs = (kt & 1) ? asb0 : asb1;
        if (kt < 7) {
            GLDS(Wbf, bn, wsb[(kt + 1) & 1], (kt + 1) * 64);
            GLDS((const ushort*)Ain, bm, nAs, (kt + 1) * 64);
        }
        __builtin_amdgcn_sched_barrier(0);
        MFMA_PHASE(Asb, wsb[kt & 1]);
        asm volatile("s_waitcnt vmcnt(0) lgkmcnt(0)" ::: "memory");
        __builtin_amdgcn_sched_barrier(0);
        __builtin_amdgcn_s_barrier();
        asm volatile("" ::: "memory");
    }

    float bsv[4];
#pragma unroll
    for (int ni = 0; ni < 4; ++ni)
        bsv[ni] = bias[bn + wn + ni * 16 + ln15];

    float* ef = (float*)lds;
#pragma unroll
    for (int half = 0; half < 2; ++half) {
        if (wm == half * 64) {
#pragma unroll
            for (int mi = 0; mi < 4; ++mi)
#pragma unroll
                for (int j = 0; j < 4; ++j) {
                    int lr = mi * 16 + ln16 * 4 + j;
#pragma unroll
                    for (int ni = 0; ni < 4; ++ni) {
                        int col = wn + ni * 16 + ln15;
                        int cs  = col ^ ((lr & 12) << 2);
                        ef[lr * 128 + cs] = acc[mi][ni][j] + bsv[ni];
                    }
                }
        }
        asm volatile("s_waitcnt lgkmcnt(0)" ::: "memory");
        __builtin_amdgcn_sched_barrier(0);
        __builtin_amdgcn_s_barrier();
        asm volatile("" ::: "memory");
#pragma unroll
        for (int i = 0; i < 8; ++i) {
            int idx = i * 1024 + tid * 4;
            int lr = idx >> 7, col = idx & 127;
            int cs = col ^ ((lr & 12) << 2);
            float4 v = *(const float4*)&ef[lr * 128 + cs];
            *(float4*)((float*)out + (long)(bm + half * 64 + lr) * 512 + bn + col) = v;
        }
        if (half == 0) {
            asm volatile("" ::: "memory");
            __builtin_amdgcn_s_barrier();
            asm volatile("" ::: "memory");
        }
    }
}

// ---------------------------------------------------------------------------
extern "C" void kernel_launch(void* const* d_in, const int* in_sizes, int n_in,
                              void* d_out, int out_size, void* d_ws, size_t ws_size,
                              hipStream_t stream) {
    const float* query = (const float*)d_in[0];
    const float* key   = (const float*)d_in[1];
    const float* value = (const float*)d_in[2];
    const int*   mask  = (const int*)d_in[3];
    const float* Wq = (const float*)d_in[4];
    const float* bq = (const float*)d_in[5];
    const float* Wk = (const float*)d_in[6];
    const float* bk = (const float*)d_in[7];
    const float* Wv = (const float*)d_in[8];
    const float* bv = (const float*)d_in[9];
    const float* Wo = (const float*)d_in[10];
    const float* bo = (const float*)d_in[11];
    float* out = (float*)d_out;

    char* ws = (char*)d_ws;
    ushort* Wqbf  = (ushort*)(ws + 0);                  // 512 KB
    ushort* Wobf  = (ushort*)(ws + 524288u);            // 512 KB
    float*  WkT   = (float*)(ws + (1u << 20));          // 1 MB
    float*  WvT   = (float*)(ws + (2u << 20));          // 1 MB
    float*  kproj = (float*)(ws + (3u << 20));          // 256 KB
    float*  vproj = (float*)(ws + (3u << 20) + 262144u);
    ushort* xbf   = (ushort*)(ws + (4u << 20));         // 8 MB (8192 x 512 bf16)

    convert2<<<dim3(256, 2), 256, 0, stream>>>(Wq, Wo, Wqbf, Wobf);
    transpose2<<<dim3(16, 16, 2), dim3(32, 8), 0, stream>>>(Wk, Wv, WkT, WvT);

    kv_proj<<<B_ * S_, 512, 0, stream>>>(key, value, WkT, WvT, bk, bv, kproj, vproj);

    // fused q-projection + two-stage attention: 1024 blocks x 8 t-rows, wave=head
    qattn<<<1024, 512, 0, stream>>>(query, Wqbf, bq, kproj, vproj, mask, xbf);

    // output projection: M = 8192, bf16 A, fp32 out
    gemm_mfma<1, 0><<<256, 256, 0, stream>>>(xbf, Wobf, bo, out, 64);

    (void)in_sizes; (void)n_in; (void)out_size; (void)ws_size;
}

// Round 14
// 114.882 us; speedup vs baseline: 1.2415x; 1.2415x over previous
//
#include <hip/hip_runtime.h>
#include <hip/hip_bf16.h>

// Problem constants
#define B_  16
#define C_  6
#define T_  512
#define S_  8

#define AS1 __attribute__((address_space(1)))
#define AS3 __attribute__((address_space(3)))

typedef __attribute__((ext_vector_type(8))) short bf16x8;
typedef __attribute__((ext_vector_type(4))) float f32x4;

__device__ __forceinline__ ushort f2bf(float f) {
    __hip_bfloat16 h = __float2bfloat16(f);
    return *reinterpret_cast<ushort*>(&h);
}
__device__ __forceinline__ float bfu2f(ushort u) {
    uint x = (uint)u << 16;
    union { uint u; float f; } c; c.u = x; return c.f;
}
__device__ __forceinline__ bf16x8 cvt8(float4 a, float4 b) {
    union { bf16x8 v; ushort u[8]; } r;
    r.u[0] = f2bf(a.x); r.u[1] = f2bf(a.y); r.u[2] = f2bf(a.z); r.u[3] = f2bf(a.w);
    r.u[4] = f2bf(b.x); r.u[5] = f2bf(b.y); r.u[6] = f2bf(b.z); r.u[7] = f2bf(b.w);
    return r.v;
}

// ---------------------------------------------------------------------------
// Two 512x512 transposes in one launch (Wk->WkT, Wv->WvT)
__global__ void transpose2(const float* __restrict__ s0, const float* __restrict__ s1,
                           float* __restrict__ d0, float* __restrict__ d1) {
    const float* src = blockIdx.z ? s1 : s0;
    float* dst = blockIdx.z ? d1 : d0;
    __shared__ float tile[32][33];
    int bx = blockIdx.x * 32, by = blockIdx.y * 32;
    int tx = threadIdx.x, ty = threadIdx.y;
    for (int i = 0; i < 32; i += 8)
        tile[ty + i][tx] = src[(long)(by + ty + i) * 512 + bx + tx];
    __syncthreads();
    for (int i = 0; i < 32; i += 8)
        dst[(long)(bx + ty + i) * 512 + by + tx] = tile[tx][ty + i];
}

// Two fp32->bf16 512x512 conversions in one launch (Wq, Wo)
__global__ void convert2(const float* __restrict__ s0, const float* __restrict__ s1,
                         ushort* __restrict__ d0, ushort* __restrict__ d1) {
    const float* s = blockIdx.y ? s1 : s0;
    ushort* d = blockIdx.y ? d1 : d0;
    int i = (blockIdx.x * 256 + threadIdx.x) * 4;
    float4 v = *(const float4*)(s + i);
    ushort4 o;
    o.x = f2bf(v.x); o.y = f2bf(v.y); o.z = f2bf(v.z); o.w = f2bf(v.w);
    *(ushort4*)(d + i) = o;
}

// ---------------------------------------------------------------------------
// K/V projections (tiny: 128 rows)
__global__ void kv_proj(const float* __restrict__ key, const float* __restrict__ value,
                        const float* __restrict__ WkT, const float* __restrict__ WvT,
                        const float* __restrict__ bk, const float* __restrict__ bv,
                        float* __restrict__ kout, float* __restrict__ vout) {
    int row = blockIdx.x;      // b*S + s
    int j = threadIdx.x;       // 0..511
    __shared__ float krow[512];
    __shared__ float vrow[512];
    krow[j] = key[(long)row * 512 + j];
    vrow[j] = value[(long)row * 512 + j];
    __syncthreads();
    float ak = bk[j], av = bv[j];
#pragma unroll 8
    for (int f = 0; f < 512; ++f) {
        ak += krow[f] * WkT[(long)f * 512 + j];
        av += vrow[f] * WvT[(long)f * 512 + j];
    }
    kout[(long)row * 512 + j] = ak;
    vout[(long)row * 512 + j] = av;
}

// ---------------------------------------------------------------------------
// MEGA-FUSED v4: block = 16 t-rows of one b; 512 threads = 8 waves; WAVE=HEAD.
// q stays in MFMA accumulators acc[6c][4nf] (v2 geometry: c = m-frag, tt =
// ln16*4+j, d = nf*16+ln15). The v2 defect (serial reg-staged phase-1) is
// replaced by a K-QUARTERED global_load_lds pipeline: A staged as FP32 in two
// 48 KB quarter-buffers (96 rows x 128 cols), DMA'd asynchronously (zero VGPR
// cost), quarter q+1 issued at the top of quarter q's GEMM, one vmcnt(0)+
// barrier per quarter. Fragments read fp32 from LDS + cvt_pk to bf16 in-loop.
// Swizzle per rule 21: linear LDS dest, inverse-permuted global source,
// XOR'd fragment read (slot^=(row&7) on 16B granularity) -> 2-way max.
__global__ __launch_bounds__(512) void qattn(const float* __restrict__ query,
                                             const ushort* __restrict__ Wqbf,
                                             const float* __restrict__ bq,
                                             const float* __restrict__ kproj,
                                             const float* __restrict__ vproj,
                                             const int* __restrict__ mask,
                                             ushort* __restrict__ xout) {
    __shared__ __align__(16) float Abuf[2][96 * 128];   // 2 x 48 KB fp32 quarters
    __shared__ int mlds[128];

    const int b   = blockIdx.x >> 5;
    const int t0  = (blockIdx.x & 31) << 4;
    const int tid = threadIdx.x;
    const int h    = tid >> 6;          // wave = head
    const int lane = tid & 63;
    const int ln15 = lane & 15;
    const int ln16 = lane >> 4;
    const int nb   = h * 64;

    // stage one K-quarter (128 floats/row) of the 96 A-rows via global_load_lds.
    // wave wv covers rows wv*12..wv*12+11; op i stages rows (wv*12+2i, +1).
    // LDS dest linear (base + lane*16B); global source chunk g swizzled so the
    // fragment read slot' = (c4&24)|((c4&7)^(r&7)) returns chunk c4.
    auto STAGEQ = [&](float* buf, int q) {
        int r = h * 12 + (lane >> 5);   // first of this lane's row (pair-half)
        int s = lane & 31;              // 16B slot within row
#pragma unroll
        for (int i = 0; i < 6; ++i) {
            int rr = r + i * 2;
            int c = rr >> 4, tt = rr & 15;
            int g = (s & 24) | ((s & 7) ^ (rr & 7));
            const float* src = query + ((long)(b * 6 + c) * 512 + t0 + tt) * 512
                             + q * 128 + g * 4;
            float* dst = buf + (h * 12 + i * 2) * 128;   // wave-uniform base
            __builtin_amdgcn_global_load_lds((AS1 const void*)src, (AS3 void*)dst, 16, 0, 0);
        }
    };

    if (tid < 128) mlds[tid] = mask[((long)b * 512 + t0 + (tid >> 3)) * 8 + (tid & 7)];

    // ---- prologue: quarter 0 ----
    STAGEQ(Abuf[0], 0);
    asm volatile("s_waitcnt vmcnt(0) lgkmcnt(0)" ::: "memory");
    __builtin_amdgcn_sched_barrier(0);
    __builtin_amdgcn_s_barrier();
    asm volatile("" ::: "memory");

    // ---- q-GEMM over 4 K-quarters, acc stays in AGPRs ----
    f32x4 acc[6][4] = {};
    uint4 br2[2][4];                    // distance-2 W ring (L2-resident Wq)
#pragma unroll
    for (int nf = 0; nf < 4; ++nf) {
        br2[0][nf] = *(const uint4*)(Wqbf + (long)(nb + nf * 16 + ln15) * 512 + ln16 * 8);
        br2[1][nf] = *(const uint4*)(Wqbf + (long)(nb + nf * 16 + ln15) * 512 + 32 + ln16 * 8);
    }

#pragma unroll
    for (int q = 0; q < 4; ++q) {
        float* buf = Abuf[q & 1];
        if (q < 3) STAGEQ(Abuf[(q + 1) & 1], q + 1);   // DMA flies under GEMM
        __builtin_amdgcn_sched_barrier(0);

        __builtin_amdgcn_s_setprio(1);
#pragma unroll
        for (int kb8 = 0; kb8 < 4; ++kb8) {
            int kb = q * 4 + kb8;
            bf16x8 af[6];
#pragma unroll
            for (int mf = 0; mf < 6; ++mf) {
                int r = mf * 16 + ln15;
                int c4a = kb8 * 8 + ln16 * 2;
                int c4b = c4a + 1;
                int sa = (c4a & 24) | ((c4a & 7) ^ (r & 7));
                int sb = (c4b & 24) | ((c4b & 7) ^ (r & 7));
                float4 lo = *(const float4*)&buf[r * 128 + sa * 4];
                float4 hi = *(const float4*)&buf[r * 128 + sb * 4];
                af[mf] = cvt8(lo, hi);
            }
#pragma unroll
            for (int mf = 0; mf < 6; ++mf)
#pragma unroll
                for (int nf = 0; nf < 4; ++nf)
                    acc[mf][nf] = __builtin_amdgcn_mfma_f32_16x16x32_bf16(
                        af[mf], *(const bf16x8*)&br2[kb & 1][nf], acc[mf][nf], 0, 0, 0);
            if (kb < 14) {
#pragma unroll
                for (int nf = 0; nf < 4; ++nf)
                    br2[kb & 1][nf] = *(const uint4*)(Wqbf + (long)(nb + nf * 16 + ln15) * 512
                                                      + (kb + 2) * 32 + ln16 * 8);
            }
        }
        __builtin_amdgcn_s_setprio(0);

        // next-quarter DMA must be complete before it becomes the read buffer
        asm volatile("s_waitcnt vmcnt(0) lgkmcnt(0)" ::: "memory");
        __builtin_amdgcn_sched_barrier(0);
        __builtin_amdgcn_s_barrier();
        asm volatile("" ::: "memory");
    }

    {
        float bqv[4];
#pragma unroll
        for (int nf = 0; nf < 4; ++nf) bqv[nf] = bq[nb + nf * 16 + ln15];
#pragma unroll
        for (int mf = 0; mf < 6; ++mf)
#pragma unroll
            for (int nf = 0; nf < 4; ++nf)
#pragma unroll
                for (int j = 0; j < 4; ++j) acc[mf][nf][j] += bqv[nf];
    }

    // ---- Phase 3: q1 = mean over c (frag-elementwise, all-local) ----
    f32x4 q1f[4];
#pragma unroll
    for (int nf = 0; nf < 4; ++nf) {
        f32x4 s = acc[0][nf];
#pragma unroll
        for (int c = 1; c < 6; ++c) s += acc[c][nf];
        q1f[nf] = s * (1.0f / 6.0f);
    }

    // ---- Phase 4: stage-1 attention (head-local) ----
    float sc[4][8];
#pragma unroll
    for (int s = 0; s < 8; ++s) {
        float kv[4];
#pragma unroll
        for (int nf = 0; nf < 4; ++nf)
            kv[nf] = kproj[(long)(b * 8 + s) * 512 + nb + nf * 16 + ln15];
#pragma unroll
        for (int j = 0; j < 4; ++j) {
            float p = q1f[0][j] * kv[0] + q1f[1][j] * kv[1]
                    + q1f[2][j] * kv[2] + q1f[3][j] * kv[3];
            p += __shfl_xor(p, 1); p += __shfl_xor(p, 2);
            p += __shfl_xor(p, 4); p += __shfl_xor(p, 8);
            sc[j][s] = p * 0.125f;
        }
    }
#pragma unroll
    for (int j = 0; j < 4; ++j) {
        int tt = ln16 * 4 + j;
        int mk[8];
        float mx = -1e30f;
#pragma unroll
        for (int s = 0; s < 8; ++s) {
            mk[s] = mlds[tt * 8 + s];
            if (mk[s] == 0) sc[j][s] = -1e30f;
            mx = fmaxf(mx, sc[j][s]);
        }
        float sum = 0.f;
#pragma unroll
        for (int s = 0; s < 8; ++s) {
            float e = __expf(sc[j][s] - mx);
            sc[j][s] = e;
            sum += e;
        }
        float inv = 1.0f / sum;
#pragma unroll
        for (int s = 0; s < 8; ++s) sc[j][s] = mk[s] ? sc[j][s] * inv : 0.f;
    }
    f32x4 pcf[4] = {};
#pragma unroll
    for (int s = 0; s < 8; ++s) {
        float vv[4];
#pragma unroll
        for (int nf = 0; nf < 4; ++nf)
            vv[nf] = vproj[(long)(b * 8 + s) * 512 + nb + nf * 16 + ln15];
#pragma unroll
        for (int nf = 0; nf < 4; ++nf)
#pragma unroll
            for (int j = 0; j < 4; ++j) pcf[nf][j] += sc[j][s] * vv[nf];
    }

    // ---- Phase 5: ss + softmax over c (all-local) ----
    float a2[4][6];
#pragma unroll
    for (int c = 0; c < 6; ++c)
#pragma unroll
        for (int j = 0; j < 4; ++j) {
            float p = pcf[0][j] * acc[c][0][j] + pcf[1][j] * acc[c][1][j]
                    + pcf[2][j] * acc[c][2][j] + pcf[3][j] * acc[c][3][j];
            p += __shfl_xor(p, 1); p += __shfl_xor(p, 2);
            p += __shfl_xor(p, 4); p += __shfl_xor(p, 8);
            a2[j][c] = p * 0.125f;
        }
#pragma unroll
    for (int j = 0; j < 4; ++j) {
        float mx = -1e30f;
#pragma unroll
        for (int c = 0; c < 6; ++c) mx = fmaxf(mx, a2[j][c]);
        float sum = 0.f;
#pragma unroll
        for (int c = 0; c < 6; ++c) {
            float e = __expf(a2[j][c] - mx);
            a2[j][c] = e;
            sum += e;
        }
        float inv = 1.0f / sum;
#pragma unroll
        for (int c = 0; c < 6; ++c) a2[j][c] *= inv;
    }

    // ---- Phase 6: x = sum_c a2_c * q_c ; stage via LDS; coalesced store ----
    ushort* xstage = (ushort*)Abuf[0];   // 16 rows x 512 bf16 = 16 KB, Abuf dead
#pragma unroll
    for (int nf = 0; nf < 4; ++nf)
#pragma unroll
        for (int j = 0; j < 4; ++j) {
            float x = 0.f;
#pragma unroll
            for (int c = 0; c < 6; ++c) x += a2[j][c] * acc[c][nf][j];
            xstage[(ln16 * 4 + j) * 512 + nb + nf * 16 + ln15] = f2bf(x);
        }
    __syncthreads();
    {
        int idx = tid * 16;
        int row = idx >> 9;
        int off = idx & 511;
        uint4 v0 = *(const uint4*)&xstage[row * 512 + off];
        uint4 v1 = *(const uint4*)&xstage[row * 512 + off + 8];
        ushort* dst = xout + ((long)(b * 512 + t0 + row)) * 512 + off;
        *(uint4*)dst = v0;
        *(uint4*)(dst + 8) = v1;
    }
}

// ---------------------------------------------------------------------------
// MFMA bf16 GEMM (R9 structure) — output projection only (ABF16 path).
template <int ABF16, int OUTBF>
__global__ __launch_bounds__(256, ABF16 ? 2 : 3)
void gemm_mfma(const void* __restrict__ Ain,
               const ushort* __restrict__ Wbf,
               const float* __restrict__ bias,
               void* __restrict__ out, int mpanels) {
    __shared__ __align__(16) ushort lds[32768];

    const int bid = blockIdx.x;
    const int cpx = (mpanels * 4) >> 3;
    const int swz = (bid & 7) * cpx + (bid >> 3);
    const int bm = (swz >> 2) * 128;
    const int bn = (swz & 3) * 128;

    const int tid  = threadIdx.x;
    const int lane = tid & 63;
    const int wv   = tid >> 6;
    const int wm   = (wv >> 1) * 64;
    const int wn   = (wv & 1) * 64;
    const int ln15 = lane & 15;
    const int ln16 = lane >> 4;

    auto GLDS = [&](const ushort* gbase, int rowbase, ushort* ldsbase, int k0) {
        int rb = wv * 32 + (lane >> 3);
        int c  = lane & 7;
#pragma unroll
        for (int i = 0; i < 4; ++i) {
            int r = rb + i * 8;
            const ushort* src = gbase + (long)(rowbase + r) * 512 + k0 + ((c ^ (r & 7)) << 3);
            ushort* dst = ldsbase + wv * 2048 + i * 512;
            __builtin_amdgcn_global_load_lds((AS1 const void*)src, (AS3 void*)dst, 16, 0, 0);
        }
    };

    ushort* asb0 = lds;
    ushort* asb1 = lds + 8192;
    ushort* wsb[2] = { lds + 16384, lds + 24576 };

    f32x4 acc[4][4] = {};

    auto MFMA_PHASE = [&](ushort* Asb, ushort* Wsb) {
        __builtin_amdgcn_s_setprio(1);
#pragma unroll
        for (int kj = 0; kj < 2; ++kj) {
            bf16x8 af[4], bfv[4];
#pragma unroll
            for (int mi = 0; mi < 4; ++mi) {
                int row = wm + mi * 16 + ln15;
                int ch  = kj * 4 + ln16;
                af[mi] = *(const bf16x8*)&Asb[row * 64 + ((ch ^ (row & 7)) << 3)];
            }
#pragma unroll
            for (int ni = 0; ni < 4; ++ni) {
                int row = wn + ni * 16 + ln15;
                int ch  = kj * 4 + ln16;
                bfv[ni] = *(const bf16x8*)&Wsb[row * 64 + ((ch ^ (row & 7)) << 3)];
            }
#pragma unroll
            for (int mi = 0; mi < 4; ++mi)
#pragma unroll
                for (int ni = 0; ni < 4; ++ni)
                    acc[mi][ni] = __builtin_amdgcn_mfma_f32_16x16x32_bf16(
                        af[mi], bfv[ni], acc[mi][ni], 0, 0, 0);
        }
        __builtin_amdgcn_s_setprio(0);
    };

    GLDS((const ushort*)Ain, bm, asb0, 0);
    GLDS(Wbf, bn, wsb[0], 0);
    asm volatile("s_waitcnt vmcnt(0) lgkmcnt(0)" ::: "memory");
    __builtin_amdgcn_sched_barrier(0);
    __builtin_amdgcn_s_barrier();
    asm volatile("" ::: "memory");
#pragma unroll
    for (int kt = 0; kt < 8; ++kt) {
        ushort* Asb = (kt & 1) ? asb1 : asb0;
        ushort* nAs = (kt & 1) ? asb0 : asb1;
        if (kt < 7) {
            GLDS(Wbf, bn, wsb[(kt + 1) & 1], (kt + 1) * 64);
            GLDS((const ushort*)Ain, bm, nAs, (kt + 1) * 64);
        }
        __builtin_amdgcn_sched_barrier(0);
        MFMA_PHASE(Asb, wsb[kt & 1]);
        asm volatile("s_waitcnt vmcnt(0) lgkmcnt(0)" ::: "memory");
        __builtin_amdgcn_sched_barrier(0);
        __builtin_amdgcn_s_barrier();
        asm volatile("" ::: "memory");
    }

    float bsv[4];
#pragma unroll
    for (int ni = 0; ni < 4; ++ni)
        bsv[ni] = bias[bn + wn + ni * 16 + ln15];

    float* ef = (float*)lds;
#pragma unroll
    for (int half = 0; half < 2; ++half) {
        if (wm == half * 64) {
#pragma unroll
            for (int mi = 0; mi < 4; ++mi)
#pragma unroll
                for (int j = 0; j < 4; ++j) {
                    int lr = mi * 16 + ln16 * 4 + j;
#pragma unroll
                    for (int ni = 0; ni < 4; ++ni) {
                        int col = wn + ni * 16 + ln15;
                        int cs  = col ^ ((lr & 12) << 2);
                        ef[lr * 128 + cs] = acc[mi][ni][j] + bsv[ni];
                    }
                }
        }
        asm volatile("s_waitcnt lgkmcnt(0)" ::: "memory");
        __builtin_amdgcn_sched_barrier(0);
        __builtin_amdgcn_s_barrier();
        asm volatile("" ::: "memory");
#pragma unroll
        for (int i = 0; i < 8; ++i) {
            int idx = i * 1024 + tid * 4;
            int lr = idx >> 7, col = idx & 127;
            int cs = col ^ ((lr & 12) << 2);
            float4 v = *(const float4*)&ef[lr * 128 + cs];
            *(float4*)((float*)out + (long)(bm + half * 64 + lr) * 512 + bn + col) = v;
        }
        if (half == 0) {
            asm volatile("" ::: "memory");
            __builtin_amdgcn_s_barrier();
            asm volatile("" ::: "memory");
        }
    }
}

// ---------------------------------------------------------------------------
extern "C" void kernel_launch(void* const* d_in, const int* in_sizes, int n_in,
                              void* d_out, int out_size, void* d_ws, size_t ws_size,
                              hipStream_t stream) {
    const float* query = (const float*)d_in[0];
    const float* key   = (const float*)d_in[1];
    const float* value = (const float*)d_in[2];
    const int*   mask  = (const int*)d_in[3];
    const float* Wq = (const float*)d_in[4];
    const float* bq = (const float*)d_in[5];
    const float* Wk = (const float*)d_in[6];
    const float* bk = (const float*)d_in[7];
    const float* Wv = (const float*)d_in[8];
    const float* bv = (const float*)d_in[9];
    const float* Wo = (const float*)d_in[10];
    const float* bo = (const float*)d_in[11];
    float* out = (float*)d_out;

    char* ws = (char*)d_ws;
    ushort* Wqbf  = (ushort*)(ws + 0);                  // 512 KB
    ushort* Wobf  = (ushort*)(ws + 524288u);            // 512 KB
    float*  WkT   = (float*)(ws + (1u << 20));          // 1 MB
    float*  WvT   = (float*)(ws + (2u << 20));          // 1 MB
    float*  kproj = (float*)(ws + (3u << 20));          // 256 KB
    float*  vproj = (float*)(ws + (3u << 20) + 262144u);
    ushort* xbf   = (ushort*)(ws + (4u << 20));         // 8 MB (8192 x 512 bf16)

    convert2<<<dim3(256, 2), 256, 0, stream>>>(Wq, Wo, Wqbf, Wobf);
    transpose2<<<dim3(16, 16, 2), dim3(32, 8), 0, stream>>>(Wk, Wv, WkT, WvT);

    kv_proj<<<B_ * S_, 512, 0, stream>>>(key, value, WkT, WvT, bk, bv, kproj, vproj);

    // fused q-projection + two-stage attention: 512 blocks x 16 t-rows, wave=head
    qattn<<<512, 512, 0, stream>>>(query, Wqbf, bq, kproj, vproj, mask, xbf);

    // output projection: M = 8192, bf16 A, fp32 out
    gemm_mfma<1, 0><<<256, 256, 0, stream>>>(xbf, Wobf, bo, out, 64);

    (void)in_sizes; (void)n_in; (void)out_size; (void)ws_size;
}

// Round 15
// 109.033 us; speedup vs baseline: 1.3081x; 1.0536x over previous
//
#include <hip/hip_runtime.h>
#include <hip/hip_bf16.h>

// Problem constants
#define B_  16
#define C_  6
#define T_  512
#define S_  8

#define AS1 __attribute__((address_space(1)))
#define AS3 __attribute__((address_space(3)))

typedef __attribute__((ext_vector_type(8))) short bf16x8;
typedef __attribute__((ext_vector_type(4))) float f32x4;

__device__ __forceinline__ ushort f2bf(float f) {
    __hip_bfloat16 h = __float2bfloat16(f);
    return *reinterpret_cast<ushort*>(&h);
}
__device__ __forceinline__ float bfu2f(ushort u) {
    uint x = (uint)u << 16;
    union { uint u; float f; } c; c.u = x; return c.f;
}

// ---------------------------------------------------------------------------
// Two 512x512 transposes in one launch (Wk->WkT, Wv->WvT)
__global__ void transpose2(const float* __restrict__ s0, const float* __restrict__ s1,
                           float* __restrict__ d0, float* __restrict__ d1) {
    const float* src = blockIdx.z ? s1 : s0;
    float* dst = blockIdx.z ? d1 : d0;
    __shared__ float tile[32][33];
    int bx = blockIdx.x * 32, by = blockIdx.y * 32;
    int tx = threadIdx.x, ty = threadIdx.y;
    for (int i = 0; i < 32; i += 8)
        tile[ty + i][tx] = src[(long)(by + ty + i) * 512 + bx + tx];
    __syncthreads();
    for (int i = 0; i < 32; i += 8)
        dst[(long)(bx + ty + i) * 512 + by + tx] = tile[tx][ty + i];
}

// Two fp32->bf16 512x512 conversions in one launch (Wq, Wo)
__global__ void convert2(const float* __restrict__ s0, const float* __restrict__ s1,
                         ushort* __restrict__ d0, ushort* __restrict__ d1) {
    const float* s = blockIdx.y ? s1 : s0;
    ushort* d = blockIdx.y ? d1 : d0;
    int i = (blockIdx.x * 256 + threadIdx.x) * 4;
    float4 v = *(const float4*)(s + i);
    ushort4 o;
    o.x = f2bf(v.x); o.y = f2bf(v.y); o.z = f2bf(v.z); o.w = f2bf(v.w);
    *(ushort4*)(d + i) = o;
}

// ---------------------------------------------------------------------------
// K/V projections (tiny: 128 rows)
__global__ void kv_proj(const float* __restrict__ key, const float* __restrict__ value,
                        const float* __restrict__ WkT, const float* __restrict__ WvT,
                        const float* __restrict__ bk, const float* __restrict__ bv,
                        float* __restrict__ kout, float* __restrict__ vout) {
    int row = blockIdx.x;      // b*S + s
    int j = threadIdx.x;       // 0..511
    __shared__ float krow[512];
    __shared__ float vrow[512];
    krow[j] = key[(long)row * 512 + j];
    vrow[j] = value[(long)row * 512 + j];
    __syncthreads();
    float ak = bk[j], av = bv[j];
#pragma unroll 8
    for (int f = 0; f < 512; ++f) {
        ak += krow[f] * WkT[(long)f * 512 + j];
        av += vrow[f] * WvT[(long)f * 512 + j];
    }
    kout[(long)row * 512 + j] = ak;
    vout[(long)row * 512 + j] = av;
}

// ---------------------------------------------------------------------------
// MEGA-FUSED v5: block = 16 t-rows of one b; 512 threads = 8 waves; WAVE=HEAD.
// q stays in MFMA accumulators acc[6c][4nf] (c = m-frag, tt = ln16*4+j,
// d = nf*16+ln15). Staging = quartered REG-STAGED BF16 (v2's cheap bf16
// ds_read frags + v4's async overlap, R6/R9-proven full-cover pattern):
//   iter q: LOADQ(q+1) issue -> GEMM(q) covers HBM latency -> WRITEQ(q+1)
//   (cvt+ds_write, reg-dep drains loads) -> __syncthreads.
// Inner loop is pure ds_read_b128(bf16)+MFMA (cvt8 eliminated from the
// critical path). W streamed from L2 via distance-3 register ring.
// LDS: 2 x 24KB quarter buffers (96 rows x 128 k-cols bf16, XOR-swizzled
// 16B chunks: s = (kc8&8)|((kc8&7)^(row&7))) + mask; ~50 KB total.
__global__ __launch_bounds__(512) void qattn(const float* __restrict__ query,
                                             const ushort* __restrict__ Wqbf,
                                             const float* __restrict__ bq,
                                             const float* __restrict__ kproj,
                                             const float* __restrict__ vproj,
                                             const int* __restrict__ mask,
                                             ushort* __restrict__ xout) {
    __shared__ __align__(16) ushort Abf[2][96 * 128];   // 2 x 24 KB bf16 quarters
    __shared__ int mlds[128];

    const int b   = blockIdx.x >> 5;
    const int t0  = (blockIdx.x & 31) << 4;
    const int tid = threadIdx.x;
    const int h    = tid >> 6;          // wave = head
    const int lane = tid & 63;
    const int ln15 = lane & 15;
    const int ln16 = lane >> 4;
    const int nb   = h * 64;

    float4 ra[6];   // quarter staging: 6 float4 per thread (24 floats)

    // coalesced fp32 loads of one K-quarter: sweep i covers 16 rows x 128 cols
    auto LOADQ = [&](int q) {
#pragma unroll
        for (int i = 0; i < 6; ++i) {
            int idx = i * 2048 + tid * 4;       // 0..12287 floats
            int row = idx >> 7;                 // 0..95 = c*16 + tt
            int col = idx & 127;
            int c = row >> 4, tt = row & 15;
            ra[i] = *(const float4*)(query + ((long)(b * 6 + c) * 512 + t0 + tt) * 512
                                     + q * 128 + col);
        }
    };
    // cvt to bf16 and write to quarter buffer with XOR-swizzled 16B chunks
    auto WRITEQ = [&](ushort* buf) {
#pragma unroll
        for (int i = 0; i < 6; ++i) {
            int idx = i * 2048 + tid * 4;
            int row = idx >> 7;
            int col = idx & 127;
            int kc8  = col >> 3;                // 16B chunk (8 bf16)
            int half = (col >> 2) & 1;
            int s = (kc8 & 8) | ((kc8 & 7) ^ (row & 7));
            ushort4 p;
            p.x = f2bf(ra[i].x); p.y = f2bf(ra[i].y);
            p.z = f2bf(ra[i].z); p.w = f2bf(ra[i].w);
            *(ushort4*)((char*)buf + row * 256 + s * 16 + half * 8) = p;
        }
    };

    if (tid < 128) mlds[tid] = mask[((long)b * 512 + t0 + (tid >> 3)) * 8 + (tid & 7)];

    // ---- prologue: quarter 0 ----
    LOADQ(0);
    WRITEQ(Abf[0]);
    __syncthreads();

    // ---- q-GEMM over 4 K-quarters, acc stays in AGPRs ----
    f32x4 acc[6][4] = {};
    uint4 br[3][4];                     // distance-3 W ring (L2-resident Wq)
#pragma unroll
    for (int kb = 0; kb < 3; ++kb)
#pragma unroll
        for (int nf = 0; nf < 4; ++nf)
            br[kb][nf] = *(const uint4*)(Wqbf + (long)(nb + nf * 16 + ln15) * 512
                                         + kb * 32 + ln16 * 8);

#pragma unroll
    for (int q = 0; q < 4; ++q) {
        const ushort* buf = Abf[q & 1];
        if (q < 3) LOADQ(q + 1);        // loads fly under this quarter's GEMM
        __builtin_amdgcn_sched_barrier(0);

        __builtin_amdgcn_s_setprio(1);
#pragma unroll
        for (int kb8 = 0; kb8 < 4; ++kb8) {
            int kb = q * 4 + kb8;
            bf16x8 af[6];
#pragma unroll
            for (int mf = 0; mf < 6; ++mf) {
                int row = mf * 16 + ln15;
                int kc8 = kb8 * 4 + ln16;
                int s = (kc8 & 8) | ((kc8 & 7) ^ (row & 7));
                af[mf] = *(const bf16x8*)((const char*)buf + row * 256 + s * 16);
            }
#pragma unroll
            for (int mf = 0; mf < 6; ++mf)
#pragma unroll
                for (int nf = 0; nf < 4; ++nf)
                    acc[mf][nf] = __builtin_amdgcn_mfma_f32_16x16x32_bf16(
                        af[mf], *(const bf16x8*)&br[kb % 3][nf], acc[mf][nf], 0, 0, 0);
            if (kb < 13) {
#pragma unroll
                for (int nf = 0; nf < 4; ++nf)
                    br[(kb + 3) % 3][nf] = *(const uint4*)(Wqbf + (long)(nb + nf * 16 + ln15) * 512
                                                           + (kb + 3) * 32 + ln16 * 8);
            }
        }
        __builtin_amdgcn_s_setprio(0);

        if (q < 3) WRITEQ(Abf[(q + 1) & 1]);   // reg-dep drains LOADQ(q+1)
        __syncthreads();
    }

    {
        float bqv[4];
#pragma unroll
        for (int nf = 0; nf < 4; ++nf) bqv[nf] = bq[nb + nf * 16 + ln15];
#pragma unroll
        for (int mf = 0; mf < 6; ++mf)
#pragma unroll
            for (int nf = 0; nf < 4; ++nf)
#pragma unroll
                for (int j = 0; j < 4; ++j) acc[mf][nf][j] += bqv[nf];
    }

    // ---- Phase 3: q1 = mean over c (frag-elementwise, all-local) ----
    f32x4 q1f[4];
#pragma unroll
    for (int nf = 0; nf < 4; ++nf) {
        f32x4 s = acc[0][nf];
#pragma unroll
        for (int c = 1; c < 6; ++c) s += acc[c][nf];
        q1f[nf] = s * (1.0f / 6.0f);
    }

    // ---- Phase 4: stage-1 attention (head-local) ----
    float sc[4][8];
#pragma unroll
    for (int s = 0; s < 8; ++s) {
        float kv[4];
#pragma unroll
        for (int nf = 0; nf < 4; ++nf)
            kv[nf] = kproj[(long)(b * 8 + s) * 512 + nb + nf * 16 + ln15];
#pragma unroll
        for (int j = 0; j < 4; ++j) {
            float p = q1f[0][j] * kv[0] + q1f[1][j] * kv[1]
                    + q1f[2][j] * kv[2] + q1f[3][j] * kv[3];
            p += __shfl_xor(p, 1); p += __shfl_xor(p, 2);
            p += __shfl_xor(p, 4); p += __shfl_xor(p, 8);
            sc[j][s] = p * 0.125f;
        }
    }
#pragma unroll
    for (int j = 0; j < 4; ++j) {
        int tt = ln16 * 4 + j;
        int mk[8];
        float mx = -1e30f;
#pragma unroll
        for (int s = 0; s < 8; ++s) {
            mk[s] = mlds[tt * 8 + s];
            if (mk[s] == 0) sc[j][s] = -1e30f;
            mx = fmaxf(mx, sc[j][s]);
        }
        float sum = 0.f;
#pragma unroll
        for (int s = 0; s < 8; ++s) {
            float e = __expf(sc[j][s] - mx);
            sc[j][s] = e;
            sum += e;
        }
        float inv = 1.0f / sum;
#pragma unroll
        for (int s = 0; s < 8; ++s) sc[j][s] = mk[s] ? sc[j][s] * inv : 0.f;
    }
    f32x4 pcf[4] = {};
#pragma unroll
    for (int s = 0; s < 8; ++s) {
        float vv[4];
#pragma unroll
        for (int nf = 0; nf < 4; ++nf)
            vv[nf] = vproj[(long)(b * 8 + s) * 512 + nb + nf * 16 + ln15];
#pragma unroll
        for (int nf = 0; nf < 4; ++nf)
#pragma unroll
            for (int j = 0; j < 4; ++j) pcf[nf][j] += sc[j][s] * vv[nf];
    }

    // ---- Phase 5: ss + softmax over c (all-local) ----
    float a2[4][6];
#pragma unroll
    for (int c = 0; c < 6; ++c)
#pragma unroll
        for (int j = 0; j < 4; ++j) {
            float p = pcf[0][j] * acc[c][0][j] + pcf[1][j] * acc[c][1][j]
                    + pcf[2][j] * acc[c][2][j] + pcf[3][j] * acc[c][3][j];
            p += __shfl_xor(p, 1); p += __shfl_xor(p, 2);
            p += __shfl_xor(p, 4); p += __shfl_xor(p, 8);
            a2[j][c] = p * 0.125f;
        }
#pragma unroll
    for (int j = 0; j < 4; ++j) {
        float mx = -1e30f;
#pragma unroll
        for (int c = 0; c < 6; ++c) mx = fmaxf(mx, a2[j][c]);
        float sum = 0.f;
#pragma unroll
        for (int c = 0; c < 6; ++c) {
            float e = __expf(a2[j][c] - mx);
            a2[j][c] = e;
            sum += e;
        }
        float inv = 1.0f / sum;
#pragma unroll
        for (int c = 0; c < 6; ++c) a2[j][c] *= inv;
    }

    // ---- Phase 6: x = sum_c a2_c * q_c ; stage via LDS; coalesced store ----
    ushort* xstage = Abf[0];   // 16 rows x 512 bf16 = 16 KB, Abf dead
#pragma unroll
    for (int nf = 0; nf < 4; ++nf)
#pragma unroll
        for (int j = 0; j < 4; ++j) {
            float x = 0.f;
#pragma unroll
            for (int c = 0; c < 6; ++c) x += a2[j][c] * acc[c][nf][j];
            xstage[(ln16 * 4 + j) * 512 + nb + nf * 16 + ln15] = f2bf(x);
        }
    __syncthreads();
    {
        int idx = tid * 16;
        int row = idx >> 9;
        int off = idx & 511;
        uint4 v0 = *(const uint4*)&xstage[row * 512 + off];
        uint4 v1 = *(const uint4*)&xstage[row * 512 + off + 8];
        ushort* dst = xout + ((long)(b * 512 + t0 + row)) * 512 + off;
        *(uint4*)dst = v0;
        *(uint4*)(dst + 8) = v1;
    }
}

// ---------------------------------------------------------------------------
// MFMA bf16 GEMM (R9 structure) — output projection only (ABF16 path).
template <int ABF16, int OUTBF>
__global__ __launch_bounds__(256, ABF16 ? 2 : 3)
void gemm_mfma(const void* __restrict__ Ain,
               const ushort* __restrict__ Wbf,
               const float* __restrict__ bias,
               void* __restrict__ out, int mpanels) {
    __shared__ __align__(16) ushort lds[32768];

    const int bid = blockIdx.x;
    const int cpx = (mpanels * 4) >> 3;
    const int swz = (bid & 7) * cpx + (bid >> 3);
    const int bm = (swz >> 2) * 128;
    const int bn = (swz & 3) * 128;

    const int tid  = threadIdx.x;
    const int lane = tid & 63;
    const int wv   = tid >> 6;
    const int wm   = (wv >> 1) * 64;
    const int wn   = (wv & 1) * 64;
    const int ln15 = lane & 15;
    const int ln16 = lane >> 4;

    auto GLDS = [&](const ushort* gbase, int rowbase, ushort* ldsbase, int k0) {
        int rb = wv * 32 + (lane >> 3);
        int c  = lane & 7;
#pragma unroll
        for (int i = 0; i < 4; ++i) {
            int r = rb + i * 8;
            const ushort* src = gbase + (long)(rowbase + r) * 512 + k0 + ((c ^ (r & 7)) << 3);
            ushort* dst = ldsbase + wv * 2048 + i * 512;
            __builtin_amdgcn_global_load_lds((AS1 const void*)src, (AS3 void*)dst, 16, 0, 0);
        }
    };

    ushort* asb0 = lds;
    ushort* asb1 = lds + 8192;
    ushort* wsb[2] = { lds + 16384, lds + 24576 };

    f32x4 acc[4][4] = {};

    auto MFMA_PHASE = [&](ushort* Asb, ushort* Wsb) {
        __builtin_amdgcn_s_setprio(1);
#pragma unroll
        for (int kj = 0; kj < 2; ++kj) {
            bf16x8 af[4], bfv[4];
#pragma unroll
            for (int mi = 0; mi < 4; ++mi) {
                int row = wm + mi * 16 + ln15;
                int ch  = kj * 4 + ln16;
                af[mi] = *(const bf16x8*)&Asb[row * 64 + ((ch ^ (row & 7)) << 3)];
            }
#pragma unroll
            for (int ni = 0; ni < 4; ++ni) {
                int row = wn + ni * 16 + ln15;
                int ch  = kj * 4 + ln16;
                bfv[ni] = *(const bf16x8*)&Wsb[row * 64 + ((ch ^ (row & 7)) << 3)];
            }
#pragma unroll
            for (int mi = 0; mi < 4; ++mi)
#pragma unroll
                for (int ni = 0; ni < 4; ++ni)
                    acc[mi][ni] = __builtin_amdgcn_mfma_f32_16x16x32_bf16(
                        af[mi], bfv[ni], acc[mi][ni], 0, 0, 0);
        }
        __builtin_amdgcn_s_setprio(0);
    };

    GLDS((const ushort*)Ain, bm, asb0, 0);
    GLDS(Wbf, bn, wsb[0], 0);
    asm volatile("s_waitcnt vmcnt(0) lgkmcnt(0)" ::: "memory");
    __builtin_amdgcn_sched_barrier(0);
    __builtin_amdgcn_s_barrier();
    asm volatile("" ::: "memory");
#pragma unroll
    for (int kt = 0; kt < 8; ++kt) {
        ushort* Asb = (kt & 1) ? asb1 : asb0;
        ushort* nAs = (kt & 1) ? asb0 : asb1;
        if (kt < 7) {
            GLDS(Wbf, bn, wsb[(kt + 1) & 1], (kt + 1) * 64);
            GLDS((const ushort*)Ain, bm, nAs, (kt + 1) * 64);
        }
        __builtin_amdgcn_sched_barrier(0);
        MFMA_PHASE(Asb, wsb[kt & 1]);
        asm volatile("s_waitcnt vmcnt(0) lgkmcnt(0)" ::: "memory");
        __builtin_amdgcn_sched_barrier(0);
        __builtin_amdgcn_s_barrier();
        asm volatile("" ::: "memory");
    }

    float bsv[4];
#pragma unroll
    for (int ni = 0; ni < 4; ++ni)
        bsv[ni] = bias[bn + wn + ni * 16 + ln15];

    float* ef = (float*)lds;
#pragma unroll
    for (int half = 0; half < 2; ++half) {
        if (wm == half * 64) {
#pragma unroll
            for (int mi = 0; mi < 4; ++mi)
#pragma unroll
                for (int j = 0; j < 4; ++j) {
                    int lr = mi * 16 + ln16 * 4 + j;
#pragma unroll
                    for (int ni = 0; ni < 4; ++ni) {
                        int col = wn + ni * 16 + ln15;
                        int cs  = col ^ ((lr & 12) << 2);
                        ef[lr * 128 + cs] = acc[mi][ni][j] + bsv[ni];
                    }
                }
        }
        asm volatile("s_waitcnt lgkmcnt(0)" ::: "memory");
        __builtin_amdgcn_sched_barrier(0);
        __builtin_amdgcn_s_barrier();
        asm volatile("" ::: "memory");
#pragma unroll
        for (int i = 0; i < 8; ++i) {
            int idx = i * 1024 + tid * 4;
            int lr = idx >> 7, col = idx & 127;
            int cs = col ^ ((lr & 12) << 2);
            float4 v = *(const float4*)&ef[lr * 128 + cs];
            *(float4*)((float*)out + (long)(bm + half * 64 + lr) * 512 + bn + col) = v;
        }
        if (half == 0) {
            asm volatile("" ::: "memory");
            __builtin_amdgcn_s_barrier();
            asm volatile("" ::: "memory");
        }
    }
}

// ---------------------------------------------------------------------------
extern "C" void kernel_launch(void* const* d_in, const int* in_sizes, int n_in,
                              void* d_out, int out_size, void* d_ws, size_t ws_size,
                              hipStream_t stream) {
    const float* query = (const float*)d_in[0];
    const float* key   = (const float*)d_in[1];
    const float* value = (const float*)d_in[2];
    const int*   mask  = (const int*)d_in[3];
    const float* Wq = (const float*)d_in[4];
    const float* bq = (const float*)d_in[5];
    const float* Wk = (const float*)d_in[6];
    const float* bk = (const float*)d_in[7];
    const float* Wv = (const float*)d_in[8];
    const float* bv = (const float*)d_in[9];
    const float* Wo = (const float*)d_in[10];
    const float* bo = (const float*)d_in[11];
    float* out = (float*)d_out;

    char* ws = (char*)d_ws;
    ushort* Wqbf  = (ushort*)(ws + 0);                  // 512 KB
    ushort* Wobf  = (ushort*)(ws + 524288u);            // 512 KB
    float*  WkT   = (float*)(ws + (1u << 20));          // 1 MB
    float*  WvT   = (float*)(ws + (2u << 20));          // 1 MB
    float*  kproj = (float*)(ws + (3u << 20));          // 256 KB
    float*  vproj = (float*)(ws + (3u << 20) + 262144u);
    ushort* xbf   = (ushort*)(ws + (4u << 20));         // 8 MB (8192 x 512 bf16)

    convert2<<<dim3(256, 2), 256, 0, stream>>>(Wq, Wo, Wqbf, Wobf);
    transpose2<<<dim3(16, 16, 2), dim3(32, 8), 0, stream>>>(Wk, Wv, WkT, WvT);

    kv_proj<<<B_ * S_, 512, 0, stream>>>(key, value, WkT, WvT, bk, bv, kproj, vproj);

    // fused q-projection + two-stage attention: 512 blocks x 16 t-rows, wave=head
    qattn<<<512, 512, 0, stream>>>(query, Wqbf, bq, kproj, vproj, mask, xbf);

    // output projection: M = 8192, bf16 A, fp32 out
    gemm_mfma<1, 0><<<256, 256, 0, stream>>>(xbf, Wobf, bo, out, 64);

    (void)in_sizes; (void)n_in; (void)out_size; (void)ws_size;
}